// Round 2
// baseline (1420.845 us; speedup 1.0000x reference)
//
#include <hip/hip_runtime.h>

// ============================================================================
// CharLevelEncoder: char-LSTM (H=256, E=64, T=16) over 32768 words + fused
// final linear. Strategy:
//  - counting-sort words by length; blocks take 2 short + 2 long 16-word
//    m-tiles (balanced-by-construction); per-step m-tile early-out.
//  - per block (64 words, 256 thr = 4 waves): gates = [x_t|h] @ Wcat^T via
//    mfma_f32_16x16x32_bf16; waves partition the 1024 gate cols so i/f/g/o of
//    one hidden unit share a lane -> cell state c lives in VGPRs all 16 steps.
//  - h exchanged via single LDS X buffer (A-frag packed layout), 2 barriers
//    per step; frozen words' h persists in LDS -> feeds fused final GEMM.
// ============================================================================

#define NW 32768

typedef __attribute__((ext_vector_type(8))) short short8;
typedef __attribute__((ext_vector_type(4))) float f32x4;

#define MFMA16(a, b, c) __builtin_amdgcn_mfma_f32_16x16x32_bf16(a, b, c, 0, 0, 0)

// ---- workspace layout (bytes) ----
#define O_CNT   0                      // u32 hist[16], pos[16], offs[16]
#define O_ORDER 256                    // i32[32768] sorted word ids (asc by len)
#define O_SLEN  (O_ORDER + 131072)     // i32[32768] sorted lengths
#define O_WCAT  (O_SLEN + 131072)      // bf16[1024][320]  [W_ih | W_hh]
#define O_WLIN  (O_WCAT + 655360)      // bf16[256][512]
#define O_ECH   (O_WLIN + 262144)      // bf16[256][64]
#define O_BIAS  (O_ECH + 32768)        // f32[1024] b_ih + b_hh
// total: 1216768 B (~1.2 MB)

__device__ inline unsigned short f2b(float f) {   // fp32 -> bf16 RNE
  unsigned u = __builtin_bit_cast(unsigned, f);
  u = u + 0x7fffu + ((u >> 16) & 1u);
  return (unsigned short)(u >> 16);
}
__device__ inline float fsigm(float x) {
  float e = __builtin_amdgcn_exp2f(-1.44269504f * x);
  return __builtin_amdgcn_rcpf(1.0f + e);
}
__device__ inline float ftanh(float x) {
  float e = __builtin_amdgcn_exp2f(2.88539008f * x);
  return 1.0f - 2.0f * __builtin_amdgcn_rcpf(e + 1.0f);
}

// ---- setup: convert weights to bf16, combine biases, zero sort counters ----
__global__ void k_prep(const float* __restrict__ wih, const float* __restrict__ whh,
                       const float* __restrict__ wlin, const float* __restrict__ ech,
                       const float* __restrict__ bih, const float* __restrict__ bhh,
                       unsigned char* __restrict__ ws) {
  int i = blockIdx.x * 256 + threadIdx.x;
  if (i < 327680) {                                   // W_cat [1024][320]
    int n = i / 320, k = i - n * 320;
    float v = (k < 64) ? wih[n * 64 + k] : whh[n * 256 + (k - 64)];
    ((unsigned short*)(ws + O_WCAT))[i] = f2b(v);
    return;
  }
  int j = i - 327680;
  if (j < 131072) { ((unsigned short*)(ws + O_WLIN))[j] = f2b(wlin[j]); return; }
  j -= 131072;
  if (j < 16384)  { ((unsigned short*)(ws + O_ECH))[j] = f2b(ech[j]); return; }
  j -= 16384;
  if (j < 1024)   { ((float*)(ws + O_BIAS))[j] = bih[j] + bhh[j]; return; }
  j -= 1024;
  if (j < 48)     { ((unsigned*)(ws + O_CNT))[j] = 0u; return; }
}

__global__ void k_hist(const int* __restrict__ lens, unsigned char* __restrict__ ws) {
  int w = blockIdx.x * 256 + threadIdx.x;
  if (w >= NW) return;
  int l = lens[w]; l = l < 1 ? 1 : (l > 16 ? 16 : l);
  atomicAdd((unsigned*)(ws + O_CNT) + (l - 1), 1u);
}

__global__ void k_scan(unsigned char* __restrict__ ws) {
  if (threadIdx.x == 0 && blockIdx.x == 0) {
    unsigned* hist = (unsigned*)(ws + O_CNT);
    unsigned* offs = hist + 32;
    unsigned s = 0;
    for (int l = 0; l < 16; ++l) { offs[l] = s; s += hist[l]; }
  }
}

__global__ void k_scatter(const int* __restrict__ lens, unsigned char* __restrict__ ws) {
  int w = blockIdx.x * 256 + threadIdx.x;
  if (w >= NW) return;
  int l = lens[w]; l = l < 1 ? 1 : (l > 16 ? 16 : l);
  unsigned* cnt = (unsigned*)(ws + O_CNT);
  unsigned p = cnt[32 + (l - 1)] + atomicAdd(&cnt[16 + (l - 1)], 1u);
  ((int*)(ws + O_ORDER))[p] = w;
  ((int*)(ws + O_SLEN))[p]  = l;
}

// ---- main fused kernel: 512 blocks x 256 threads, 64 words/block ----
__global__ __launch_bounds__(256, 2) void k_main(
    const int* __restrict__ cidx, const float* __restrict__ wemb,
    const float* __restrict__ blin, float* __restrict__ outp,
    const unsigned char* __restrict__ ws) {
  // X buffer, MFMA-A-fragment packed: element (word m, k) at
  // [mt=m>>4][kb=k>>5][(m&15)+16*((k>>3)&3)][k&7].  k: 0..63 = x_t, 64..319 = h
  __shared__ unsigned short Xb[4][10][64][8];   // 40 KiB -> 2 blocks/CU

  const int tid = threadIdx.x, b = blockIdx.x;
  const int wave = tid >> 6, lane = tid & 63;
  const int q = lane >> 4, l15 = lane & 15;

  const int* order = (const int*)(ws + O_ORDER);
  const int* slen  = (const int*)(ws + O_SLEN);
  const unsigned short* wcat = (const unsigned short*)(ws + O_WCAT);
  const unsigned short* wlin = (const unsigned short*)(ws + O_WLIN);
  const unsigned short* ech  = (const unsigned short*)(ws + O_ECH);
  const float* biasg = (const float*)(ws + O_BIAS);

  // block b: m-tiles 0,1 from short end, 2,3 from long end of sorted order
  int pb[4];
  pb[0] = 32 * b;           pb[1] = pb[0] + 16;
  pb[2] = NW - 32 * b - 32; pb[3] = pb[2] + 16;

  int tmax[4]; unsigned lenpk[4];
  #pragma unroll
  for (int mt = 0; mt < 4; ++mt) {
    tmax[mt] = slen[pb[mt] + 15];                 // ascending within tile
    unsigned l0 = (unsigned)slen[pb[mt] + q * 4 + 0];
    unsigned l1 = (unsigned)slen[pb[mt] + q * 4 + 1];
    unsigned l2 = (unsigned)slen[pb[mt] + q * 4 + 2];
    unsigned l3 = (unsigned)slen[pb[mt] + q * 4 + 3];
    lenpk[mt] = l0 | (l1 << 8) | (l2 << 16) | (l3 << 24);
  }
  const int Tm = tmax[3];                         // global max for this block

  // per-lane gate biases (wave owns hidden [wave*64, wave*64+64))
  float bi[4], bff[4], bgg[4], boo[4];
  #pragma unroll
  for (int cc = 0; cc < 4; ++cc) {
    int hid = wave * 64 + cc * 16 + l15;
    bi[cc]  = biasg[hid];
    bff[cc] = biasg[256 + hid];
    bgg[cc] = biasg[512 + hid];
    boo[cc] = biasg[768 + hid];
  }

  // char-gather setup: thread -> (row rr, quarter gp) of the x region
  const int rr = tid >> 2, gp = tid & 3;
  const int gmt = rr >> 4, gmi = rr & 15;
  const int gword = order[pb[gmt] + gmi];
  const int* gchar = cidx + gword * 16;
  unsigned short* gdst0 = &Xb[gmt][gp >> 1][gmi + 16 * ((gp & 1) * 2)][0];
  unsigned short* gdst1 = &Xb[gmt][gp >> 1][gmi + 16 * ((gp & 1) * 2 + 1)][0];

  { // zero X (h region must start 0)
    short8 z = 0;
    short8* px = (short8*)&Xb[0][0][0][0];
    #pragma unroll
    for (int i = 0; i < 10; ++i) px[tid + 256 * i] = z;
  }
  __syncthreads();
  { // gather x for t=0
    int c0 = gchar[0];
    const short8* src = (const short8*)(ech + c0 * 64 + gp * 16);
    *(short8*)gdst0 = src[0];
    *(short8*)gdst1 = src[1];
  }
  __syncthreads();

  f32x4 creg[4][4];                                // cell state [chunk][mtile]
  #pragma unroll
  for (int cc = 0; cc < 4; ++cc)
    #pragma unroll
    for (int mt = 0; mt < 4; ++mt) creg[cc][mt] = 0.0f;

  unsigned hst[4][4][2];                           // stashed bf16 h pairs

  for (int t = 0; t < Tm; ++t) {
    bool actm[4];
    actm[0] = t < tmax[0]; actm[1] = t < tmax[1];
    actm[2] = t < tmax[2]; actm[3] = true;

    #pragma unroll
    for (int cc = 0; cc < 4; ++cc) {               // 16 hidden units per chunk
      const unsigned short* wb0 = wcat + (wave * 64 + cc * 16 + l15) * 320 + q * 8;
      const unsigned short* wb1 = wb0 + 256 * 320;
      const unsigned short* wb2 = wb1 + 256 * 320;
      const unsigned short* wb3 = wb2 + 256 * 320;

      f32x4 ac[4][4];                              // [mtile][gate]
      #pragma unroll
      for (int mt = 0; mt < 4; ++mt)
        #pragma unroll
        for (int g = 0; g < 4; ++g) ac[mt][g] = 0.0f;

      #pragma unroll
      for (int kb = 0; kb < 10; ++kb) {
        short8 B0 = *(const short8*)(wb0 + kb * 32);
        short8 B1 = *(const short8*)(wb1 + kb * 32);
        short8 B2 = *(const short8*)(wb2 + kb * 32);
        short8 B3 = *(const short8*)(wb3 + kb * 32);
        #pragma unroll
        for (int mt = 0; mt < 4; ++mt) {
          if (actm[mt]) {                          // wave-uniform branch
            short8 A = *(const short8*)&Xb[mt][kb][lane][0];
            ac[mt][0] = MFMA16(A, B0, ac[mt][0]);
            ac[mt][1] = MFMA16(A, B1, ac[mt][1]);
            ac[mt][2] = MFMA16(A, B2, ac[mt][2]);
            ac[mt][3] = MFMA16(A, B3, ac[mt][3]);
          }
        }
      }
      // elementwise LSTM update (C-layout: row = q*4+r, col = l15)
      #pragma unroll
      for (int mt = 0; mt < 4; ++mt) {
        if (!actm[mt]) continue;
        unsigned hp0 = 0, hp1 = 0;
        #pragma unroll
        for (int r = 0; r < 4; ++r) {
          float gi = ac[mt][0][r] + bi[cc];
          float gf = ac[mt][1][r] + bff[cc];
          float gg = ac[mt][2][r] + bgg[cc];
          float go = ac[mt][3][r] + boo[cc];
          float si = fsigm(gi), sf = fsigm(gf);
          float sg = ftanh(gg), so = fsigm(go);
          float cold = creg[cc][mt][r];
          float cn = sf * cold + si * sg;
          float hn = so * ftanh(cn);
          int lene = (int)((lenpk[mt] >> (8 * r)) & 255u);
          bool ae = t < lene;                      // freeze past word length
          creg[cc][mt][r] = ae ? cn : cold;
          unsigned hb = (unsigned)f2b(hn);
          if (r == 0) hp0 = hb;
          if (r == 1) hp0 |= hb << 16;
          if (r == 2) hp1 = hb;
          if (r == 3) hp1 |= hb << 16;
        }
        hst[cc][mt][0] = hp0; hst[cc][mt][1] = hp1;
      }
    } // cc

    __syncthreads();                               // all X reads of step t done

    // write new h into X (predicated: frozen words keep final h in LDS)
    #pragma unroll
    for (int cc = 0; cc < 4; ++cc) {
      int hid = wave * 64 + cc * 16 + l15;
      int kb = 2 + (hid >> 5);
      int qf = (hid >> 3) & 3;
      int jj = hid & 7;
      #pragma unroll
      for (int mt = 0; mt < 4; ++mt) {
        if (!actm[mt]) continue;
        #pragma unroll
        for (int r = 0; r < 4; ++r) {
          int lene = (int)((lenpk[mt] >> (8 * r)) & 255u);
          if (t < lene) {
            unsigned v = hst[cc][mt][r >> 1] >> (16 * (r & 1));
            Xb[mt][kb][q * 4 + r + 16 * qf][jj] = (unsigned short)v;
          }
        }
      }
    }
    // gather x for step t+1
    if (t + 1 < Tm) {
      int c1 = gchar[t + 1];
      const short8* src = (const short8*)(ech + c1 * 64 + gp * 16);
      *(short8*)gdst0 = src[0];
      *(short8*)gdst1 = src[1];
    }
    __syncthreads();                               // writes visible for t+1
  } // t

  // ---- fused final linear: out = relu([word_emb | h] @ W_lin^T + b_lin) ----
  int widA[4];
  #pragma unroll
  for (int mt = 0; mt < 4; ++mt) widA[mt] = order[pb[mt] + l15];
  float blv[4];
  #pragma unroll
  for (int nt = 0; nt < 4; ++nt) blv[nt] = blin[wave * 64 + nt * 16 + l15];

  f32x4 fac[4][4];
  #pragma unroll
  for (int mt = 0; mt < 4; ++mt)
    #pragma unroll
    for (int nt = 0; nt < 4; ++nt) fac[mt][nt] = 0.0f;

  #pragma unroll
  for (int kf = 0; kf < 16; ++kf) {                // K = 512
    short8 Bn[4];
    #pragma unroll
    for (int nt = 0; nt < 4; ++nt)
      Bn[nt] = *(const short8*)(wlin + (wave * 64 + nt * 16 + l15) * 512 + kf * 32 + q * 8);
    short8 Am[4];
    #pragma unroll
    for (int mt = 0; mt < 4; ++mt) {
      if (kf < 8) {                                // word_emb fp32 -> bf16
        const float* pa = wemb + widA[mt] * 256 + kf * 32 + q * 8;
        f32x4 f0 = *(const f32x4*)pa;
        f32x4 f1 = *(const f32x4*)(pa + 4);
        short8 A;
        A[0] = (short)f2b(f0[0]); A[1] = (short)f2b(f0[1]);
        A[2] = (short)f2b(f0[2]); A[3] = (short)f2b(f0[3]);
        A[4] = (short)f2b(f1[0]); A[5] = (short)f2b(f1[1]);
        A[6] = (short)f2b(f1[2]); A[7] = (short)f2b(f1[3]);
        Am[mt] = A;
      } else {                                     // final h from LDS X
        Am[mt] = *(const short8*)&Xb[mt][kf - 6][lane][0];
      }
    }
    #pragma unroll
    for (int mt = 0; mt < 4; ++mt)
      #pragma unroll
      for (int nt = 0; nt < 4; ++nt)
        fac[mt][nt] = MFMA16(Am[mt], Bn[nt], fac[mt][nt]);
  }
  // epilogue: bias + relu + scatter to original word rows
  #pragma unroll
  for (int mt = 0; mt < 4; ++mt) {
    #pragma unroll
    for (int r = 0; r < 4; ++r) {
      int wid = order[pb[mt] + q * 4 + r];
      float* po = outp + wid * 256 + wave * 64 + l15;
      #pragma unroll
      for (int nt = 0; nt < 4; ++nt) {
        float v = fac[mt][nt][r] + blv[nt];
        po[nt * 16] = v > 0.0f ? v : 0.0f;
      }
    }
  }
}

extern "C" void kernel_launch(void* const* d_in, const int* in_sizes, int n_in,
                              void* d_out, int out_size, void* d_ws, size_t ws_size,
                              hipStream_t stream) {
  const int*   cidx = (const int*)d_in[0];
  const int*   clen = (const int*)d_in[1];
  const float* wemb = (const float*)d_in[2];
  const float* ech  = (const float*)d_in[3];
  const float* wih  = (const float*)d_in[4];
  const float* whh  = (const float*)d_in[5];
  const float* bih  = (const float*)d_in[6];
  const float* bhh  = (const float*)d_in[7];
  const float* wlin = (const float*)d_in[8];
  const float* blin = (const float*)d_in[9];
  float* outp = (float*)d_out;
  unsigned char* ws = (unsigned char*)d_ws;

  k_prep<<<1861, 256, 0, stream>>>(wih, whh, wlin, ech, bih, bhh, ws);
  k_hist<<<128, 256, 0, stream>>>(clen, ws);
  k_scan<<<1, 64, 0, stream>>>(ws);
  k_scatter<<<128, 256, 0, stream>>>(clen, ws);
  k_main<<<512, 256, 0, stream>>>(cidx, wemb, blin, outp, ws);
}

// Round 3
// 1339.384 us; speedup vs baseline: 1.0608x; 1.0608x over previous
//
#include <hip/hip_runtime.h>

// ============================================================================
// CharLevelEncoder: char-LSTM (H=256, E=64, T=16) over 32768 words + fused
// final linear.
// R3: 512-thr blocks (16 waves/CU), length-homogeneous descending slices,
//     nontemporal epilogue (protect W_cat L2 residency), merged sort kernel.
// ============================================================================

#define NW 32768

typedef __attribute__((ext_vector_type(8))) short short8;
typedef __attribute__((ext_vector_type(4))) float f32x4;

#define MFMA16(a, b, c) __builtin_amdgcn_mfma_f32_16x16x32_bf16(a, b, c, 0, 0, 0)

// ---- workspace layout (bytes) ----
#define O_ORDER 256                    // i32[32768] sorted word ids (asc by len)
#define O_SLEN  (O_ORDER + 131072)     // i32[32768] sorted lengths
#define O_WCAT  (O_SLEN + 131072)      // bf16[1024][320]  [W_ih | W_hh]
#define O_WLIN  (O_WCAT + 655360)      // bf16[256][512]
#define O_ECH   (O_WLIN + 262144)      // bf16[256][64]
#define O_BIAS  (O_ECH + 32768)        // f32[1024] b_ih + b_hh

__device__ inline unsigned short f2b(float f) {   // fp32 -> bf16 RNE
  unsigned u = __builtin_bit_cast(unsigned, f);
  u = u + 0x7fffu + ((u >> 16) & 1u);
  return (unsigned short)(u >> 16);
}
__device__ inline float fsigm(float x) {
  float e = __builtin_amdgcn_exp2f(-1.44269504f * x);
  return __builtin_amdgcn_rcpf(1.0f + e);
}
__device__ inline float ftanh(float x) {
  float e = __builtin_amdgcn_exp2f(2.88539008f * x);
  return 1.0f - 2.0f * __builtin_amdgcn_rcpf(e + 1.0f);
}

// ---- setup: convert weights to bf16, combine biases ----
__global__ void k_prep(const float* __restrict__ wih, const float* __restrict__ whh,
                       const float* __restrict__ wlin, const float* __restrict__ ech,
                       const float* __restrict__ bih, const float* __restrict__ bhh,
                       unsigned char* __restrict__ ws) {
  int i = blockIdx.x * 256 + threadIdx.x;
  if (i < 327680) {                                   // W_cat [1024][320]
    int n = i / 320, k = i - n * 320;
    float v = (k < 64) ? wih[n * 64 + k] : whh[n * 256 + (k - 64)];
    ((unsigned short*)(ws + O_WCAT))[i] = f2b(v);
    return;
  }
  int j = i - 327680;
  if (j < 131072) { ((unsigned short*)(ws + O_WLIN))[j] = f2b(wlin[j]); return; }
  j -= 131072;
  if (j < 16384)  { ((unsigned short*)(ws + O_ECH))[j] = f2b(ech[j]); return; }
  j -= 16384;
  if (j < 1024)   { ((float*)(ws + O_BIAS))[j] = bih[j] + bhh[j]; return; }
}

// ---- single-block counting sort by length (LDS hist/scan/scatter) ----
__global__ void k_sort(const int* __restrict__ lens, unsigned char* __restrict__ ws) {
  __shared__ unsigned hist[16], pos[16];
  int tid = threadIdx.x;
  if (tid < 16) hist[tid] = 0;
  __syncthreads();
  for (int w = tid; w < NW; w += 1024) {
    int l = lens[w]; l = l < 1 ? 1 : (l > 16 ? 16 : l);
    atomicAdd(&hist[l - 1], 1u);
  }
  __syncthreads();
  if (tid == 0) {
    unsigned acc = 0;
    for (int l = 0; l < 16; ++l) { pos[l] = acc; acc += hist[l]; }
  }
  __syncthreads();
  int* order = (int*)(ws + O_ORDER);
  int* slenp = (int*)(ws + O_SLEN);
  for (int w = tid; w < NW; w += 1024) {
    int l = lens[w]; l = l < 1 ? 1 : (l > 16 ? 16 : l);
    unsigned p = atomicAdd(&pos[l - 1], 1u);
    order[p] = w; slenp[p] = l;
  }
}

// ---- main fused kernel: 512 blocks x 512 threads, 64 words/block ----
__global__ __launch_bounds__(512, 4) void k_main(
    const int* __restrict__ cidx, const float* __restrict__ wemb,
    const float* __restrict__ blin, float* __restrict__ outp,
    const unsigned char* __restrict__ ws) {
  // X buffer, MFMA-A-fragment packed: element (word m, k) at
  // [mt=m>>4][kb=k>>5][(m&15)+16*((k>>3)&3)][k&7].  k: 0..63 = x_t, 64..319 = h
  __shared__ unsigned short Xb[4][10][64][8];   // 40 KiB -> 2 blocks/CU

  const int tid = threadIdx.x, b = blockIdx.x;
  const int wave = tid >> 6, lane = tid & 63;
  const int q = lane >> 4, l15 = lane & 15;

  const int* order = (const int*)(ws + O_ORDER);
  const int* slen  = (const int*)(ws + O_SLEN);
  const unsigned short* wcat = (const unsigned short*)(ws + O_WCAT);
  const unsigned short* wlin = (const unsigned short*)(ws + O_WLIN);
  const unsigned short* ech  = (const unsigned short*)(ws + O_ECH);
  const float* biasg = (const float*)(ws + O_BIAS);

  // homogeneous 64-word slice, descending length; pair long+short per CU
  const int s = (b < 256) ? b : (767 - b);
  const int base = NW - 64 * (s + 1);
  int pb[4];
  #pragma unroll
  for (int mt = 0; mt < 4; ++mt) pb[mt] = base + 16 * mt;

  int tmax[4]; unsigned lenpk[4];
  #pragma unroll
  for (int mt = 0; mt < 4; ++mt) {
    tmax[mt] = slen[pb[mt] + 15];                 // ascending within tile
    unsigned l0 = (unsigned)slen[pb[mt] + q * 4 + 0];
    unsigned l1 = (unsigned)slen[pb[mt] + q * 4 + 1];
    unsigned l2 = (unsigned)slen[pb[mt] + q * 4 + 2];
    unsigned l3 = (unsigned)slen[pb[mt] + q * 4 + 3];
    lenpk[mt] = l0 | (l1 << 8) | (l2 << 16) | (l3 << 24);
  }
  const int Tm = tmax[3];

  // per-lane gate biases (wave owns hidden [wave*32, wave*32+32))
  float bi[2], bff[2], bgg[2], boo[2];
  #pragma unroll
  for (int cc = 0; cc < 2; ++cc) {
    int hid = wave * 32 + cc * 16 + l15;
    bi[cc]  = biasg[hid];
    bff[cc] = biasg[256 + hid];
    bgg[cc] = biasg[512 + hid];
    boo[cc] = biasg[768 + hid];
  }

  // char-gather setup (first 256 threads): thread -> (row rr, quarter gp)
  const int rr = (tid & 255) >> 2, gp = tid & 3;
  const int gmt = rr >> 4, gmi = rr & 15;
  const int gword = order[pb[gmt] + gmi];
  const int* gchar = cidx + gword * 16;
  unsigned short* gdst0 = &Xb[gmt][gp >> 1][gmi + 16 * ((gp & 1) * 2)][0];
  unsigned short* gdst1 = &Xb[gmt][gp >> 1][gmi + 16 * ((gp & 1) * 2 + 1)][0];

  { // zero X (h region must start 0)
    short8 z = 0;
    short8* px = (short8*)&Xb[0][0][0][0];
    #pragma unroll
    for (int i = 0; i < 5; ++i) px[tid + 512 * i] = z;
  }
  __syncthreads();
  if (tid < 256) { // gather x for t=0
    int c0 = gchar[0];
    const short8* src = (const short8*)(ech + c0 * 64 + gp * 16);
    *(short8*)gdst0 = src[0];
    *(short8*)gdst1 = src[1];
  }
  __syncthreads();

  f32x4 creg[2][4];                                // cell state [chunk][mtile]
  #pragma unroll
  for (int cc = 0; cc < 2; ++cc)
    #pragma unroll
    for (int mt = 0; mt < 4; ++mt) creg[cc][mt] = 0.0f;

  unsigned hst[2][4][2];                           // stashed bf16 h pairs

  for (int t = 0; t < Tm; ++t) {
    bool actm[4];
    actm[0] = t < tmax[0]; actm[1] = t < tmax[1];
    actm[2] = t < tmax[2]; actm[3] = true;

    #pragma unroll
    for (int cc = 0; cc < 2; ++cc) {               // 16 hidden units per chunk
      const unsigned short* wb0 = wcat + (wave * 32 + cc * 16 + l15) * 320 + q * 8;
      const unsigned short* wb1 = wb0 + 256 * 320;
      const unsigned short* wb2 = wb1 + 256 * 320;
      const unsigned short* wb3 = wb2 + 256 * 320;

      f32x4 ac[4][4];                              // [mtile][gate]
      #pragma unroll
      for (int mt = 0; mt < 4; ++mt)
        #pragma unroll
        for (int g = 0; g < 4; ++g) ac[mt][g] = 0.0f;

      #pragma unroll
      for (int kb = 0; kb < 10; ++kb) {
        short8 B0 = *(const short8*)(wb0 + kb * 32);
        short8 B1 = *(const short8*)(wb1 + kb * 32);
        short8 B2 = *(const short8*)(wb2 + kb * 32);
        short8 B3 = *(const short8*)(wb3 + kb * 32);
        #pragma unroll
        for (int mt = 0; mt < 4; ++mt) {
          if (actm[mt]) {                          // wave-uniform branch
            short8 A = *(const short8*)&Xb[mt][kb][lane][0];
            ac[mt][0] = MFMA16(A, B0, ac[mt][0]);
            ac[mt][1] = MFMA16(A, B1, ac[mt][1]);
            ac[mt][2] = MFMA16(A, B2, ac[mt][2]);
            ac[mt][3] = MFMA16(A, B3, ac[mt][3]);
          }
        }
      }
      // elementwise LSTM update (C-layout: row = q*4+r, col = l15)
      #pragma unroll
      for (int mt = 0; mt < 4; ++mt) {
        if (!actm[mt]) continue;
        unsigned hp0 = 0, hp1 = 0;
        #pragma unroll
        for (int r = 0; r < 4; ++r) {
          float gi = ac[mt][0][r] + bi[cc];
          float gf = ac[mt][1][r] + bff[cc];
          float gg = ac[mt][2][r] + bgg[cc];
          float go = ac[mt][3][r] + boo[cc];
          float si = fsigm(gi), sf = fsigm(gf);
          float sg = ftanh(gg), so = fsigm(go);
          float cold = creg[cc][mt][r];
          float cn = sf * cold + si * sg;
          float hn = so * ftanh(cn);
          int lene = (int)((lenpk[mt] >> (8 * r)) & 255u);
          bool ae = t < lene;                      // freeze past word length
          creg[cc][mt][r] = ae ? cn : cold;
          unsigned hb = (unsigned)f2b(hn);
          if (r == 0) hp0 = hb;
          if (r == 1) hp0 |= hb << 16;
          if (r == 2) hp1 = hb;
          if (r == 3) hp1 |= hb << 16;
        }
        hst[cc][mt][0] = hp0; hst[cc][mt][1] = hp1;
      }
    } // cc

    __syncthreads();                               // all X reads of step t done

    // write new h into X (predicated: frozen words keep final h in LDS)
    #pragma unroll
    for (int cc = 0; cc < 2; ++cc) {
      int hid = wave * 32 + cc * 16 + l15;
      int kb = 2 + (hid >> 5);
      int qf = (hid >> 3) & 3;
      int jj = hid & 7;
      #pragma unroll
      for (int mt = 0; mt < 4; ++mt) {
        if (!actm[mt]) continue;
        #pragma unroll
        for (int r = 0; r < 4; ++r) {
          int lene = (int)((lenpk[mt] >> (8 * r)) & 255u);
          if (t < lene) {
            unsigned v = hst[cc][mt][r >> 1] >> (16 * (r & 1));
            Xb[mt][kb][q * 4 + r + 16 * qf][jj] = (unsigned short)v;
          }
        }
      }
    }
    // gather x for step t+1
    if (t + 1 < Tm && tid < 256) {
      int c1 = gchar[t + 1];
      const short8* src = (const short8*)(ech + c1 * 64 + gp * 16);
      *(short8*)gdst0 = src[0];
      *(short8*)gdst1 = src[1];
    }
    __syncthreads();                               // writes visible for t+1
  } // t

  // ---- fused final linear: out = relu([word_emb | h] @ W_lin^T + b_lin) ----
  // waves 0-3: m-tiles 0,1; waves 4-7: m-tiles 2,3; wave&3 picks 64 out cols
  const int mh = wave >> 2, nw = wave & 3;
  int widA[2];
  #pragma unroll
  for (int mi = 0; mi < 2; ++mi) widA[mi] = order[pb[2 * mh + mi] + l15];
  float blv[4];
  #pragma unroll
  for (int nt = 0; nt < 4; ++nt) blv[nt] = blin[nw * 64 + nt * 16 + l15];

  f32x4 fac[2][4];
  #pragma unroll
  for (int mi = 0; mi < 2; ++mi)
    #pragma unroll
    for (int nt = 0; nt < 4; ++nt) fac[mi][nt] = 0.0f;

  #pragma unroll
  for (int kf = 0; kf < 16; ++kf) {                // K = 512
    short8 Bn[4];
    #pragma unroll
    for (int nt = 0; nt < 4; ++nt)
      Bn[nt] = *(const short8*)(wlin + (nw * 64 + nt * 16 + l15) * 512 + kf * 32 + q * 8);
    short8 Am[2];
    #pragma unroll
    for (int mi = 0; mi < 2; ++mi) {
      if (kf < 8) {                                // word_emb fp32 -> bf16 (nt)
        const f32x4* pa = (const f32x4*)(wemb + widA[mi] * 256 + kf * 32 + q * 8);
        f32x4 f0 = __builtin_nontemporal_load(pa);
        f32x4 f1 = __builtin_nontemporal_load(pa + 1);
        short8 A;
        A[0] = (short)f2b(f0[0]); A[1] = (short)f2b(f0[1]);
        A[2] = (short)f2b(f0[2]); A[3] = (short)f2b(f0[3]);
        A[4] = (short)f2b(f1[0]); A[5] = (short)f2b(f1[1]);
        A[6] = (short)f2b(f1[2]); A[7] = (short)f2b(f1[3]);
        Am[mi] = A;
      } else {                                     // final h from LDS X
        Am[mi] = *(const short8*)&Xb[2 * mh + mi][kf - 6][lane][0];
      }
    }
    #pragma unroll
    for (int mi = 0; mi < 2; ++mi)
      #pragma unroll
      for (int nt = 0; nt < 4; ++nt)
        fac[mi][nt] = MFMA16(Am[mi], Bn[nt], fac[mi][nt]);
  }
  // epilogue: bias + relu + nontemporal scatter to original word rows
  #pragma unroll
  for (int mi = 0; mi < 2; ++mi) {
    #pragma unroll
    for (int r = 0; r < 4; ++r) {
      int wid = order[pb[2 * mh + mi] + q * 4 + r];
      float* po = outp + wid * 256 + nw * 64 + l15;
      #pragma unroll
      for (int nt = 0; nt < 4; ++nt) {
        float v = fac[mi][nt][r] + blv[nt];
        v = v > 0.0f ? v : 0.0f;
        __builtin_nontemporal_store(v, po + nt * 16);
      }
    }
  }
}

extern "C" void kernel_launch(void* const* d_in, const int* in_sizes, int n_in,
                              void* d_out, int out_size, void* d_ws, size_t ws_size,
                              hipStream_t stream) {
  const int*   cidx = (const int*)d_in[0];
  const int*   clen = (const int*)d_in[1];
  const float* wemb = (const float*)d_in[2];
  const float* ech  = (const float*)d_in[3];
  const float* wih  = (const float*)d_in[4];
  const float* whh  = (const float*)d_in[5];
  const float* bih  = (const float*)d_in[6];
  const float* bhh  = (const float*)d_in[7];
  const float* wlin = (const float*)d_in[8];
  const float* blin = (const float*)d_in[9];
  float* outp = (float*)d_out;
  unsigned char* ws = (unsigned char*)d_ws;

  k_prep<<<1860, 256, 0, stream>>>(wih, whh, wlin, ech, bih, bhh, ws);
  k_sort<<<1, 1024, 0, stream>>>(clen, ws);
  k_main<<<512, 512, 0, stream>>>(cidx, wemb, blin, outp, ws);
}

// Round 4
// 1313.721 us; speedup vs baseline: 1.0815x; 1.0195x over previous
//
#include <hip/hip_runtime.h>

// ============================================================================
// CharLevelEncoder: char-LSTM (H=256, E=64, T=16) over 32768 words + fused
// final linear.
// R4: pre-pack W_cat/W_lin into MFMA-B-fragment-linear order so per-wave
//     B loads are contiguous 1024-B bursts (was: 16-segment scatter, the
//     measured 3 B/cyc/CU bottleneck). Plain output stores (L2 merges lines).
// ============================================================================

#define NW 32768

typedef __attribute__((ext_vector_type(8))) short short8;
typedef __attribute__((ext_vector_type(4))) float f32x4;

#define MFMA16(a, b, c) __builtin_amdgcn_mfma_f32_16x16x32_bf16(a, b, c, 0, 0, 0)

// ---- workspace layout (bytes) ----
#define O_ORDER 256                    // i32[32768] sorted word ids (asc by len)
#define O_SLEN  (O_ORDER + 131072)     // i32[32768] sorted lengths
#define O_WCAT  (O_SLEN + 131072)      // bf16 packed W_cat fragments (327680)
#define O_WLIN  (O_WCAT + 655360)      // bf16 packed W_lin fragments (131072)
#define O_ECH   (O_WLIN + 262144)      // bf16[256][64]
#define O_BIAS  (O_ECH + 32768)        // f32[1024] b_ih + b_hh

__device__ inline unsigned short f2b(float f) {   // fp32 -> bf16 RNE
  unsigned u = __builtin_bit_cast(unsigned, f);
  u = u + 0x7fffu + ((u >> 16) & 1u);
  return (unsigned short)(u >> 16);
}
__device__ inline float fsigm(float x) {
  float e = __builtin_amdgcn_exp2f(-1.44269504f * x);
  return __builtin_amdgcn_rcpf(1.0f + e);
}
__device__ inline float ftanh(float x) {
  float e = __builtin_amdgcn_exp2f(2.88539008f * x);
  return 1.0f - 2.0f * __builtin_amdgcn_rcpf(e + 1.0f);
}

// ---- setup: pack weights into B-fragment-linear bf16, combine biases ----
// PW index: ((((wave*2+cc)*10+kb)*4+g)*64+lane)*8+j
//   gate row n = g*256 + (wave*2+cc)*16 + (lane&15); k = kb*32 + (lane>>4)*8 + j
// PL index: (((nw*4+nt)*16+kf)*64+lane)*8+j
//   row n = nw*64+nt*16+(lane&15); k = kf*32 + (lane>>4)*8 + j
__global__ void k_prep(const float* __restrict__ wih, const float* __restrict__ whh,
                       const float* __restrict__ wlin, const float* __restrict__ ech,
                       const float* __restrict__ bih, const float* __restrict__ bhh,
                       unsigned char* __restrict__ ws) {
  int i = blockIdx.x * 256 + threadIdx.x;
  if (i < 327680) {                                   // packed W_cat
    int j = i & 7, lane = (i >> 3) & 63, t = i >> 9;
    int g = t & 3, u = t >> 2;
    int kb = u % 10, wc = u / 10;
    int n = g * 256 + wc * 16 + (lane & 15);
    int k = kb * 32 + (lane >> 4) * 8 + j;
    float v = (k < 64) ? wih[n * 64 + k] : whh[n * 256 + (k - 64)];
    ((unsigned short*)(ws + O_WCAT))[i] = f2b(v);
    return;
  }
  int i2 = i - 327680;
  if (i2 < 131072) {                                  // packed W_lin
    int j = i2 & 7, lane = (i2 >> 3) & 63, t = i2 >> 9;
    int kf = t & 15, nn = t >> 4;
    int n = (nn >> 2) * 64 + (nn & 3) * 16 + (lane & 15);
    int k = kf * 32 + (lane >> 4) * 8 + j;
    ((unsigned short*)(ws + O_WLIN))[i2] = f2b(wlin[n * 512 + k]);
    return;
  }
  int j = i2 - 131072;
  if (j < 16384)  { ((unsigned short*)(ws + O_ECH))[j] = f2b(ech[j]); return; }
  j -= 16384;
  if (j < 1024)   { ((float*)(ws + O_BIAS))[j] = bih[j] + bhh[j]; return; }
}

// ---- single-block counting sort by length (LDS hist/scan/scatter) ----
__global__ void k_sort(const int* __restrict__ lens, unsigned char* __restrict__ ws) {
  __shared__ unsigned hist[16], pos[16];
  int tid = threadIdx.x;
  if (tid < 16) hist[tid] = 0;
  __syncthreads();
  for (int w = tid; w < NW; w += 1024) {
    int l = lens[w]; l = l < 1 ? 1 : (l > 16 ? 16 : l);
    atomicAdd(&hist[l - 1], 1u);
  }
  __syncthreads();
  if (tid == 0) {
    unsigned acc = 0;
    for (int l = 0; l < 16; ++l) { pos[l] = acc; acc += hist[l]; }
  }
  __syncthreads();
  int* order = (int*)(ws + O_ORDER);
  int* slenp = (int*)(ws + O_SLEN);
  for (int w = tid; w < NW; w += 1024) {
    int l = lens[w]; l = l < 1 ? 1 : (l > 16 ? 16 : l);
    unsigned p = atomicAdd(&pos[l - 1], 1u);
    order[p] = w; slenp[p] = l;
  }
}

// ---- main fused kernel: 512 blocks x 512 threads, 64 words/block ----
__global__ __launch_bounds__(512, 4) void k_main(
    const int* __restrict__ cidx, const float* __restrict__ wemb,
    const float* __restrict__ blin, float* __restrict__ outp,
    const unsigned char* __restrict__ ws) {
  // X buffer, MFMA-A-fragment packed: element (word m, k) at
  // [mt=m>>4][kb=k>>5][(m&15)+16*((k>>3)&3)][k&7].  k: 0..63 = x_t, 64..319 = h
  __shared__ unsigned short Xb[4][10][64][8];   // 40 KiB -> 2 blocks/CU

  const int tid = threadIdx.x, b = blockIdx.x;
  const int wave = tid >> 6, lane = tid & 63;
  const int q = lane >> 4, l15 = lane & 15;

  const int* order = (const int*)(ws + O_ORDER);
  const int* slen  = (const int*)(ws + O_SLEN);
  const unsigned short* wcat = (const unsigned short*)(ws + O_WCAT);
  const unsigned short* wlin = (const unsigned short*)(ws + O_WLIN);
  const unsigned short* ech  = (const unsigned short*)(ws + O_ECH);
  const float* biasg = (const float*)(ws + O_BIAS);

  // homogeneous 64-word slice, descending length; pair long+short per CU
  const int s = (b < 256) ? b : (767 - b);
  const int base = NW - 64 * (s + 1);
  int pb[4];
  #pragma unroll
  for (int mt = 0; mt < 4; ++mt) pb[mt] = base + 16 * mt;

  int tmax[4]; unsigned lenpk[4];
  #pragma unroll
  for (int mt = 0; mt < 4; ++mt) {
    tmax[mt] = slen[pb[mt] + 15];                 // ascending within tile
    unsigned l0 = (unsigned)slen[pb[mt] + q * 4 + 0];
    unsigned l1 = (unsigned)slen[pb[mt] + q * 4 + 1];
    unsigned l2 = (unsigned)slen[pb[mt] + q * 4 + 2];
    unsigned l3 = (unsigned)slen[pb[mt] + q * 4 + 3];
    lenpk[mt] = l0 | (l1 << 8) | (l2 << 16) | (l3 << 24);
  }
  const int Tm = tmax[3];

  // per-lane gate biases (wave owns hidden [wave*32, wave*32+32))
  float bi[2], bff[2], bgg[2], boo[2];
  #pragma unroll
  for (int cc = 0; cc < 2; ++cc) {
    int hid = wave * 32 + cc * 16 + l15;
    bi[cc]  = biasg[hid];
    bff[cc] = biasg[256 + hid];
    bgg[cc] = biasg[512 + hid];
    boo[cc] = biasg[768 + hid];
  }

  // char-gather setup (first 256 threads): thread -> (row rr, quarter gp)
  const int rr = (tid & 255) >> 2, gp = tid & 3;
  const int gmt = rr >> 4, gmi = rr & 15;
  const int gword = order[pb[gmt] + gmi];
  const int* gchar = cidx + gword * 16;
  unsigned short* gdst0 = &Xb[gmt][gp >> 1][gmi + 16 * ((gp & 1) * 2)][0];
  unsigned short* gdst1 = &Xb[gmt][gp >> 1][gmi + 16 * ((gp & 1) * 2 + 1)][0];

  { // zero X (h region must start 0)
    short8 z = 0;
    short8* px = (short8*)&Xb[0][0][0][0];
    #pragma unroll
    for (int i = 0; i < 5; ++i) px[tid + 512 * i] = z;
  }
  __syncthreads();
  if (tid < 256) { // gather x for t=0
    int c0 = gchar[0];
    const short8* src = (const short8*)(ech + c0 * 64 + gp * 16);
    *(short8*)gdst0 = src[0];
    *(short8*)gdst1 = src[1];
  }
  __syncthreads();

  f32x4 creg[2][4];                                // cell state [chunk][mtile]
  #pragma unroll
  for (int cc = 0; cc < 2; ++cc)
    #pragma unroll
    for (int mt = 0; mt < 4; ++mt) creg[cc][mt] = 0.0f;

  unsigned hst[2][4][2];                           // stashed bf16 h pairs

  for (int t = 0; t < Tm; ++t) {
    bool actm[4];
    actm[0] = t < tmax[0]; actm[1] = t < tmax[1];
    actm[2] = t < tmax[2]; actm[3] = true;

    #pragma unroll
    for (int cc = 0; cc < 2; ++cc) {               // 16 hidden units per chunk
      // packed-W slice for this (wave, cc): 10 kb x 4 gates x 64 lanes x 16B,
      // each load below is a contiguous 1024-B wave burst.
      const short8* wbp = (const short8*)wcat + (wave * 2 + cc) * 2560;

      f32x4 ac[4][4];                              // [mtile][gate]
      #pragma unroll
      for (int mt = 0; mt < 4; ++mt)
        #pragma unroll
        for (int g = 0; g < 4; ++g) ac[mt][g] = 0.0f;

      #pragma unroll
      for (int kb = 0; kb < 10; ++kb) {
        const short8* pB = wbp + kb * 256;
        short8 B0 = pB[lane];
        short8 B1 = pB[64 + lane];
        short8 B2 = pB[128 + lane];
        short8 B3 = pB[192 + lane];
        #pragma unroll
        for (int mt = 0; mt < 4; ++mt) {
          if (actm[mt]) {                          // wave-uniform branch
            short8 A = *(const short8*)&Xb[mt][kb][lane][0];
            ac[mt][0] = MFMA16(A, B0, ac[mt][0]);
            ac[mt][1] = MFMA16(A, B1, ac[mt][1]);
            ac[mt][2] = MFMA16(A, B2, ac[mt][2]);
            ac[mt][3] = MFMA16(A, B3, ac[mt][3]);
          }
        }
      }
      // elementwise LSTM update (C-layout: row = q*4+r, col = l15)
      #pragma unroll
      for (int mt = 0; mt < 4; ++mt) {
        if (!actm[mt]) continue;
        unsigned hp0 = 0, hp1 = 0;
        #pragma unroll
        for (int r = 0; r < 4; ++r) {
          float gi = ac[mt][0][r] + bi[cc];
          float gf = ac[mt][1][r] + bff[cc];
          float gg = ac[mt][2][r] + bgg[cc];
          float go = ac[mt][3][r] + boo[cc];
          float si = fsigm(gi), sf = fsigm(gf);
          float sg = ftanh(gg), so = fsigm(go);
          float cold = creg[cc][mt][r];
          float cn = sf * cold + si * sg;
          float hn = so * ftanh(cn);
          int lene = (int)((lenpk[mt] >> (8 * r)) & 255u);
          bool ae = t < lene;                      // freeze past word length
          creg[cc][mt][r] = ae ? cn : cold;
          unsigned hb = (unsigned)f2b(hn);
          if (r == 0) hp0 = hb;
          if (r == 1) hp0 |= hb << 16;
          if (r == 2) hp1 = hb;
          if (r == 3) hp1 |= hb << 16;
        }
        hst[cc][mt][0] = hp0; hst[cc][mt][1] = hp1;
      }
    } // cc

    __syncthreads();                               // all X reads of step t done

    // write new h into X (predicated: frozen words keep final h in LDS)
    #pragma unroll
    for (int cc = 0; cc < 2; ++cc) {
      int hid = wave * 32 + cc * 16 + l15;
      int kb = 2 + (hid >> 5);
      int qf = (hid >> 3) & 3;
      int jj = hid & 7;
      #pragma unroll
      for (int mt = 0; mt < 4; ++mt) {
        if (!actm[mt]) continue;
        #pragma unroll
        for (int r = 0; r < 4; ++r) {
          int lene = (int)((lenpk[mt] >> (8 * r)) & 255u);
          if (t < lene) {
            unsigned v = hst[cc][mt][r >> 1] >> (16 * (r & 1));
            Xb[mt][kb][q * 4 + r + 16 * qf][jj] = (unsigned short)v;
          }
        }
      }
    }
    // gather x for step t+1
    if (t + 1 < Tm && tid < 256) {
      int c1 = gchar[t + 1];
      const short8* src = (const short8*)(ech + c1 * 64 + gp * 16);
      *(short8*)gdst0 = src[0];
      *(short8*)gdst1 = src[1];
    }
    __syncthreads();                               // writes visible for t+1
  } // t

  // ---- fused final linear: out = relu([word_emb | h] @ W_lin^T + b_lin) ----
  // waves 0-3: m-tiles 0,1; waves 4-7: m-tiles 2,3; wave&3 picks 64 out cols
  const int mh = wave >> 2, nw = wave & 3;
  int widA[2];
  #pragma unroll
  for (int mi = 0; mi < 2; ++mi) widA[mi] = order[pb[2 * mh + mi] + l15];
  float blv[4];
  #pragma unroll
  for (int nt = 0; nt < 4; ++nt) blv[nt] = blin[nw * 64 + nt * 16 + l15];

  f32x4 fac[2][4];
  #pragma unroll
  for (int mi = 0; mi < 2; ++mi)
    #pragma unroll
    for (int nt = 0; nt < 4; ++nt) fac[mi][nt] = 0.0f;

  #pragma unroll
  for (int kf = 0; kf < 16; ++kf) {                // K = 512
    short8 Bn[4];
    #pragma unroll
    for (int nt = 0; nt < 4; ++nt)                 // packed: contiguous burst
      Bn[nt] = ((const short8*)wlin)[((nw * 4 + nt) * 16 + kf) * 64 + lane];
    short8 Am[2];
    #pragma unroll
    for (int mi = 0; mi < 2; ++mi) {
      if (kf < 8) {                                // word_emb fp32 -> bf16 (nt)
        const f32x4* pa = (const f32x4*)(wemb + widA[mi] * 256 + kf * 32 + q * 8);
        f32x4 f0 = __builtin_nontemporal_load(pa);
        f32x4 f1 = __builtin_nontemporal_load(pa + 1);
        short8 A;
        A[0] = (short)f2b(f0[0]); A[1] = (short)f2b(f0[1]);
        A[2] = (short)f2b(f0[2]); A[3] = (short)f2b(f0[3]);
        A[4] = (short)f2b(f1[0]); A[5] = (short)f2b(f1[1]);
        A[6] = (short)f2b(f1[2]); A[7] = (short)f2b(f1[3]);
        Am[mi] = A;
      } else {                                     // final h from LDS X
        Am[mi] = *(const short8*)&Xb[2 * mh + mi][kf - 6][lane][0];
      }
    }
    #pragma unroll
    for (int mi = 0; mi < 2; ++mi)
      #pragma unroll
      for (int nt = 0; nt < 4; ++nt)
        fac[mi][nt] = MFMA16(Am[mi], Bn[nt], fac[mi][nt]);
  }
  // epilogue: bias + relu + scatter to original word rows (plain stores:
  // let L2 merge the 64-B quarters into full lines)
  #pragma unroll
  for (int mi = 0; mi < 2; ++mi) {
    #pragma unroll
    for (int r = 0; r < 4; ++r) {
      int wid = order[pb[2 * mh + mi] + q * 4 + r];
      float* po = outp + wid * 256 + nw * 64 + l15;
      #pragma unroll
      for (int nt = 0; nt < 4; ++nt) {
        float v = fac[mi][nt][r] + blv[nt];
        po[nt * 16] = v > 0.0f ? v : 0.0f;
      }
    }
  }
}

extern "C" void kernel_launch(void* const* d_in, const int* in_sizes, int n_in,
                              void* d_out, int out_size, void* d_ws, size_t ws_size,
                              hipStream_t stream) {
  const int*   cidx = (const int*)d_in[0];
  const int*   clen = (const int*)d_in[1];
  const float* wemb = (const float*)d_in[2];
  const float* ech  = (const float*)d_in[3];
  const float* wih  = (const float*)d_in[4];
  const float* whh  = (const float*)d_in[5];
  const float* bih  = (const float*)d_in[6];
  const float* bhh  = (const float*)d_in[7];
  const float* wlin = (const float*)d_in[8];
  const float* blin = (const float*)d_in[9];
  float* outp = (float*)d_out;
  unsigned char* ws = (unsigned char*)d_ws;

  k_prep<<<1860, 256, 0, stream>>>(wih, whh, wlin, ech, bih, bhh, ws);
  k_sort<<<1, 1024, 0, stream>>>(clen, ws);
  k_main<<<512, 512, 0, stream>>>(cidx, wemb, blin, outp, ws);
}

// Round 5
// 449.665 us; speedup vs baseline: 3.1598x; 2.9216x over previous
//
#include <hip/hip_runtime.h>

// ============================================================================
// CharLevelEncoder R5: persistent weight-stationary design.
// Evidence R2-R4: time == hbm_bytes / 2.5 TB/s; the 640-KB W_cat is re-fetched
// from HBM every step (L2 never holds it). Fix: W quantized to i8 (320 KB),
// resident per-CU in VGPRs (kb0-6) + LDS (kb7-9) for the WHOLE kernel.
// Grid 256 x 512thr, 1 block/CU (136 KB LDS), each block chains slices
// {b, 511-b} (counting-sorted by length -> balanced ~17 steps).
// i8 quant: W' = [W_ih/4 | W_hh], per-row scale u=rowmax/127; a' = [4x | h],
// uniform scale 1/127  =>  gate = (u/127)*acc + bias  (single i32 acc).
// ============================================================================

#define NW 32768

typedef __attribute__((ext_vector_type(8))) short short8;
typedef __attribute__((ext_vector_type(4))) float f32x4;
typedef __attribute__((ext_vector_type(4))) int i32x4;

#define MFMA16(a,b,c) __builtin_amdgcn_mfma_f32_16x16x32_bf16(a,b,c,0,0,0)
#define MFMAI8(a,b,c) __builtin_amdgcn_mfma_i32_16x16x32_i8(a,b,c,0,0,0)

// ---- workspace layout (bytes) ----
#define O_ORDER 0                      // i32[32768] sorted word ids (asc len)
#define O_SLEN  131072                 // i32[32768] sorted lengths
#define O_WPK   262144                 // i8 packed W' fragments (327680)
#define O_USTP  589824                 // f32[1024] u' = rowmax/(127*127)
#define O_BIAS  593920                 // f32[1024] b_ih + b_hh
#define O_CHT   598016                 // i8[256][64] chartab = rint(508*E)
#define O_WLIN  614400                 // bf16 packed W_lin fragments (131072)
// total 876544 B

__device__ inline unsigned short f2b(float f) {   // fp32 -> bf16 RNE
  unsigned u = __builtin_bit_cast(unsigned, f);
  u = u + 0x7fffu + ((u >> 16) & 1u);
  return (unsigned short)(u >> 16);
}
__device__ inline float fsigm(float x) {
  float e = __builtin_amdgcn_exp2f(-1.44269504f * x);
  return __builtin_amdgcn_rcpf(1.0f + e);
}
__device__ inline float ftanh(float x) {
  float e = __builtin_amdgcn_exp2f(2.88539008f * x);
  return 1.0f - 2.0f * __builtin_amdgcn_rcpf(e + 1.0f);
}

// ---- prep0: row scales, bias, char table ----
__global__ void k_prep0(const float* __restrict__ wih, const float* __restrict__ whh,
                        const float* __restrict__ bih, const float* __restrict__ bhh,
                        const float* __restrict__ ech, unsigned char* __restrict__ ws) {
  int i = blockIdx.x * 256 + threadIdx.x;
  if (i < 1024) {
    float mx = 0.f;
    for (int k = 0; k < 64; ++k)  mx = fmaxf(mx, fabsf(wih[i * 64 + k]) * 0.25f);
    for (int k = 0; k < 256; ++k) mx = fmaxf(mx, fabsf(whh[i * 256 + k]));
    ((float*)(ws + O_USTP))[i] = mx / (127.f * 127.f);   // u' (dequant factor)
    ((float*)(ws + O_BIAS))[i] = bih[i] + bhh[i];
    return;
  }
  int j = i - 1024;
  if (j < 16384) {                     // chartab: x' = 4x, i8 at scale 1/127
    float v = 508.f * ech[j];
    int q = (int)__builtin_rintf(v);
    q = q < -127 ? -127 : (q > 127 ? 127 : q);
    ((signed char*)(ws + O_CHT))[j] = (signed char)q;
  }
}

// ---- prep1: pack W' i8 fragments + W_lin bf16 fragments ----
// WPK flat: (((w*10+kb)*8+nt)*64+lane)*8+j ; n=(nt>>1)*256+w*32+(nt&1)*16+(lane&15)
//           k = kb*32+(lane>>4)*8+j ; val = k<64 ? wih/4 : whh
__global__ void k_prep1(const float* __restrict__ wih, const float* __restrict__ whh,
                        const float* __restrict__ wlin, unsigned char* __restrict__ ws) {
  int i = blockIdx.x * 256 + threadIdx.x;
  if (i < 327680) {
    int j = i & 7, lane = (i >> 3) & 63, t2 = i >> 9;
    int nt = t2 & 7, u2 = t2 >> 3;
    int kb = u2 % 10, w = u2 / 10;
    int n = (nt >> 1) * 256 + w * 32 + (nt & 1) * 16 + (lane & 15);
    int k = kb * 32 + (lane >> 4) * 8 + j;
    float v = (k < 64) ? wih[n * 64 + k] * 0.25f : whh[n * 256 + (k - 64)];
    float ustep = ((const float*)(ws + O_USTP))[n] * 127.f;  // rowmax/127
    float qf = (ustep > 0.f) ? v / ustep : 0.f;
    int q = (int)__builtin_rintf(qf);
    q = q < -127 ? -127 : (q > 127 ? 127 : q);
    ((signed char*)(ws + O_WPK))[i] = (signed char)q;
    return;
  }
  int i2 = i - 327680;
  if (i2 < 131072) {                   // W_lin pack (verified in R4)
    int j = i2 & 7, lane = (i2 >> 3) & 63, t3 = i2 >> 9;
    int kf = t3 & 15, nn = t3 >> 4;
    int n = (nn >> 2) * 64 + (nn & 3) * 16 + (lane & 15);
    int k = kf * 32 + (lane >> 4) * 8 + j;
    ((unsigned short*)(ws + O_WLIN))[i2] = f2b(wlin[n * 512 + k]);
  }
}

// ---- counting sort by length ----
__global__ void k_sort(const int* __restrict__ lens, unsigned char* __restrict__ ws) {
  __shared__ unsigned hist[16], pos[16];
  int tid = threadIdx.x;
  if (tid < 16) hist[tid] = 0;
  __syncthreads();
  for (int w = tid; w < NW; w += 1024) {
    int l = lens[w]; l = l < 1 ? 1 : (l > 16 ? 16 : l);
    atomicAdd(&hist[l - 1], 1u);
  }
  __syncthreads();
  if (tid == 0) {
    unsigned acc = 0;
    for (int l = 0; l < 16; ++l) { pos[l] = acc; acc += hist[l]; }
  }
  __syncthreads();
  int* order = (int*)(ws + O_ORDER);
  int* slenp = (int*)(ws + O_SLEN);
  for (int w = tid; w < NW; w += 1024) {
    int l = lens[w]; l = l < 1 ? 1 : (l > 16 ? 16 : l);
    unsigned p = atomicAdd(&pos[l - 1], 1u);
    order[p] = w; slenp[p] = l;
  }
}

// ---- main persistent kernel: 256 blocks x 512 threads ----
__global__ __launch_bounds__(512, 2) void k_main(
    const int* __restrict__ cidx, const float* __restrict__ wemb,
    const float* __restrict__ blin, float* __restrict__ outp,
    const unsigned char* __restrict__ ws) {
  extern __shared__ signed char smem[];
  // WL: [kb-7][w][nt][lane][8]  96 KB  (W' kb 7..9)
  signed char (*WL)[8][8][64][8] = (signed char (*)[8][8][64][8])smem;
  // Xb: [mt][kb][ (m&15)+16*((k&31)>>3) ][ (k&31)&7 ]  i8  20 KB
  signed char (*Xb)[10][64][8] = (signed char (*)[10][64][8])(smem + 98304);
  signed char (*CT)[64] = (signed char (*)[64])(smem + 98304 + 20480);  // 16 KB
  int (*CW)[16] = (int (*)[16])(smem + 98304 + 20480 + 16384);          //  4 KB

  const int tid = threadIdx.x, b = blockIdx.x;
  const int w = tid >> 6, lane = tid & 63;
  const int q = lane >> 4, l15 = lane & 15;

  const int* order = (const int*)(ws + O_ORDER);
  const int* slen  = (const int*)(ws + O_SLEN);
  const signed char* wpk = (const signed char*)(ws + O_WPK);
  const float* upt = (const float*)(ws + O_USTP);
  const float* bsg = (const float*)(ws + O_BIAS);
  const unsigned short* wlin = (const unsigned short*)(ws + O_WLIN);

  // ---- prologue: chartab -> LDS, W kb0-6 -> VGPR, W kb7-9 -> LDS ----
  {
    long* d = (long*)&CT[0][0];
    const long* s = (const long*)(ws + O_CHT);
    #pragma unroll
    for (int ii = 0; ii < 4; ++ii) d[tid + 512 * ii] = s[tid + 512 * ii];
  }
  long wreg[7][8];
  #pragma unroll
  for (int kb = 0; kb < 7; ++kb)
    #pragma unroll
    for (int nt = 0; nt < 8; ++nt)
      wreg[kb][nt] = *(const long*)(wpk + (((w * 10 + kb) * 8 + nt) * 64 + lane) * 8);
  #pragma unroll
  for (int c = 0; c < 24; ++c) {
    int kb = c >> 3, nt = c & 7;
    *(long*)&WL[kb][w][nt][lane][0] =
        *(const long*)(wpk + (((w * 10 + 7 + kb) * 8 + nt) * 64 + lane) * 8);
  }
  float uq[8], bq[8];
  #pragma unroll
  for (int nt = 0; nt < 8; ++nt) {
    int n = (nt >> 1) * 256 + w * 32 + (nt & 1) * 16 + l15;
    uq[nt] = upt[n]; bq[nt] = bsg[n];
  }
  const int mh = w >> 2, nw = w & 3;
  float blv[4];
  #pragma unroll
  for (int nt = 0; nt < 4; ++nt) blv[nt] = blin[nw * 64 + nt * 16 + l15];

  // ---- two balanced slices: {b, 511-b} ----
  for (int sl = 0; sl < 2; ++sl) {
    const int s = sl ? (511 - b) : b;
    const int base = 64 * s;
    __syncthreads();                    // prologue / previous epilogue done

    { // zero Xb h-region (kb 2..9): 2048 longs
      long* p = (long*)&Xb[0][0][0][0];
      #pragma unroll
      for (int ii = 0; ii < 4; ++ii) {
        int idx = tid + 512 * ii;
        int mt = idx >> 9, rem = idx & 511;
        p[mt * 640 + 128 + rem] = 0L;
      }
    }
    if (tid < 256) {                    // load this slice's char indices
      int m = tid >> 2, part = tid & 3;
      int wid = order[base + m];
      *(i32x4*)&CW[m][part * 4] = *(const i32x4*)(cidx + wid * 16 + part * 4);
    }
    int tmax[4]; unsigned lenpk[4];
    #pragma unroll
    for (int mt = 0; mt < 4; ++mt) {
      int pbm = base + 16 * mt;
      tmax[mt] = slen[pbm + 15];
      unsigned l0 = (unsigned)slen[pbm + q * 4 + 0];
      unsigned l1 = (unsigned)slen[pbm + q * 4 + 1];
      unsigned l2 = (unsigned)slen[pbm + q * 4 + 2];
      unsigned l3 = (unsigned)slen[pbm + q * 4 + 3];
      lenpk[mt] = l0 | (l1 << 8) | (l2 << 16) | (l3 << 24);
    }
    const int Tm = tmax[3];
    __syncthreads();                    // CW + zeroing visible
    {                                   // stage x̂ for t=0
      int m = tid >> 3, c = tid & 7, kb = c >> 2, kq = c & 3;
      int ch = CW[m][0] & 255;
      *(long*)&Xb[m >> 4][kb][(m & 15) + 16 * kq][0] = *(const long*)&CT[ch][kb * 32 + kq * 8];
    }
    __syncthreads();

    float creg[4][2][4];
    #pragma unroll
    for (int mt = 0; mt < 4; ++mt)
      #pragma unroll
      for (int hs = 0; hs < 2; ++hs)
        #pragma unroll
        for (int r = 0; r < 4; ++r) creg[mt][hs][r] = 0.f;
    unsigned hpack[4][2];

    for (int t = 0; t < Tm; ++t) {
      bool actm[4];
      actm[0] = t < tmax[0]; actm[1] = t < tmax[1];
      actm[2] = t < tmax[2]; actm[3] = true;

      #pragma unroll
      for (int mt = 0; mt < 4; ++mt) {
        if (!actm[mt]) continue;        // wave-uniform
        i32x4 acc[8];
        #pragma unroll
        for (int nt = 0; nt < 8; ++nt) acc[nt] = (i32x4)0;
        #pragma unroll
        for (int kb = 0; kb < 7; ++kb) {
          long A = *(const long*)&Xb[mt][kb][lane][0];
          #pragma unroll
          for (int nt = 0; nt < 8; ++nt) acc[nt] = MFMAI8(A, wreg[kb][nt], acc[nt]);
        }
        #pragma unroll
        for (int kb = 7; kb < 10; ++kb) {
          long A = *(const long*)&Xb[mt][kb][lane][0];
          #pragma unroll
          for (int nt = 0; nt < 8; ++nt) {
            long Bv = *(const long*)&WL[kb - 7][w][nt][lane][0];
            acc[nt] = MFMAI8(A, Bv, acc[nt]);
          }
        }
        // gates + LSTM update; C-layout row = q*4+r, col = l15
        #pragma unroll
        for (int hs = 0; hs < 2; ++hs) {
          unsigned hp = 0;
          #pragma unroll
          for (int r = 0; r < 4; ++r) {
            float gi = (float)acc[0 + hs][r] * uq[0 + hs] + bq[0 + hs];
            float gf = (float)acc[2 + hs][r] * uq[2 + hs] + bq[2 + hs];
            float gg = (float)acc[4 + hs][r] * uq[4 + hs] + bq[4 + hs];
            float go = (float)acc[6 + hs][r] * uq[6 + hs] + bq[6 + hs];
            float si = fsigm(gi), sf = fsigm(gf);
            float sg = ftanh(gg), so = fsigm(go);
            float cold = creg[mt][hs][r];
            float cn = sf * cold + si * sg;
            float hn = so * ftanh(cn);
            int lene = (int)((lenpk[mt] >> (8 * r)) & 255u);
            creg[mt][hs][r] = (t < lene) ? cn : cold;
            int hq = (int)__builtin_rintf(127.f * hn);
            hq = hq < -127 ? -127 : (hq > 127 ? 127 : hq);
            hp |= ((unsigned)hq & 255u) << (8 * r);
          }
          hpack[mt][hs] = hp;
        }
      } // mt
      __syncthreads();                  // all Xb reads of step t done

      // h write-back: wave w owns kb = 2+w exclusively
      #pragma unroll
      for (int mt = 0; mt < 4; ++mt) {
        if (!actm[mt]) continue;
        #pragma unroll
        for (int hs = 0; hs < 2; ++hs) {
          int kqp = hs * 2 + (l15 >> 3);
          #pragma unroll
          for (int r = 0; r < 4; ++r) {
            int lene = (int)((lenpk[mt] >> (8 * r)) & 255u);
            if (t < lene)
              Xb[mt][2 + w][(q * 4 + r) + 16 * kqp][l15 & 7] =
                  (signed char)((hpack[mt][hs] >> (8 * r)) & 255u);
          }
        }
      }
      if (t + 1 < Tm) {                 // stage x̂ for t+1
        int m = tid >> 3, c = tid & 7, kb = c >> 2, kq = c & 3;
        int ch = CW[m][t + 1] & 255;
        *(long*)&Xb[m >> 4][kb][(m & 15) + 16 * kq][0] = *(const long*)&CT[ch][kb * 32 + kq * 8];
      }
      __syncthreads();
    } // t

    // ---- fused final linear for this slice (bf16 MFMA) ----
    int widA[2];
    #pragma unroll
    for (int mi = 0; mi < 2; ++mi) widA[mi] = order[base + (2 * mh + mi) * 16 + l15];
    f32x4 fac[2][4];
    #pragma unroll
    for (int mi = 0; mi < 2; ++mi)
      #pragma unroll
      for (int nt = 0; nt < 4; ++nt) fac[mi][nt] = 0.0f;

    #pragma unroll
    for (int kf = 0; kf < 16; ++kf) {
      short8 Bn[4];
      #pragma unroll
      for (int nt = 0; nt < 4; ++nt)
        Bn[nt] = ((const short8*)wlin)[((nw * 4 + nt) * 16 + kf) * 64 + lane];
      short8 Am[2];
      #pragma unroll
      for (int mi = 0; mi < 2; ++mi) {
        if (kf < 8) {                   // word_emb fp32 -> bf16
          const f32x4* pa = (const f32x4*)(wemb + widA[mi] * 256 + kf * 32 + q * 8);
          f32x4 f0 = pa[0], f1 = pa[1];
          short8 A;
          A[0] = (short)f2b(f0[0]); A[1] = (short)f2b(f0[1]);
          A[2] = (short)f2b(f0[2]); A[3] = (short)f2b(f0[3]);
          A[4] = (short)f2b(f1[0]); A[5] = (short)f2b(f1[1]);
          A[6] = (short)f2b(f1[2]); A[7] = (short)f2b(f1[3]);
          Am[mi] = A;
        } else {                        // final h from Xb i8 -> bf16
          long ch = *(const long*)&Xb[2 * mh + mi][kf - 6][lane][0];
          short8 A;
          #pragma unroll
          for (int j = 0; j < 8; ++j) {
            int v = (int)(signed char)((ch >> (8 * j)) & 255);
            A[j] = (short)f2b((float)v * (1.f / 127.f));
          }
          Am[mi] = A;
        }
      }
      #pragma unroll
      for (int mi = 0; mi < 2; ++mi)
        #pragma unroll
        for (int nt = 0; nt < 4; ++nt)
          fac[mi][nt] = MFMA16(Am[mi], Bn[nt], fac[mi][nt]);
    }
    #pragma unroll
    for (int mi = 0; mi < 2; ++mi) {
      #pragma unroll
      for (int r = 0; r < 4; ++r) {
        int wid = order[base + (2 * mh + mi) * 16 + q * 4 + r];
        float* po = outp + wid * 256 + nw * 64 + l15;
        #pragma unroll
        for (int nt = 0; nt < 4; ++nt) {
          float v = fac[mi][nt][r] + blv[nt];
          po[nt * 16] = v > 0.f ? v : 0.f;
        }
      }
    }
  } // slice
}

extern "C" void kernel_launch(void* const* d_in, const int* in_sizes, int n_in,
                              void* d_out, int out_size, void* d_ws, size_t ws_size,
                              hipStream_t stream) {
  const int*   cidx = (const int*)d_in[0];
  const int*   clen = (const int*)d_in[1];
  const float* wemb = (const float*)d_in[2];
  const float* ech  = (const float*)d_in[3];
  const float* wih  = (const float*)d_in[4];
  const float* whh  = (const float*)d_in[5];
  const float* bih  = (const float*)d_in[6];
  const float* bhh  = (const float*)d_in[7];
  const float* wlin = (const float*)d_in[8];
  const float* blin = (const float*)d_in[9];
  float* outp = (float*)d_out;
  unsigned char* ws = (unsigned char*)d_ws;

  k_prep0<<<68, 256, 0, stream>>>(wih, whh, bih, bhh, ech, ws);
  k_prep1<<<1792, 256, 0, stream>>>(wih, whh, wlin, ws);
  k_sort<<<1, 1024, 0, stream>>>(clen, ws);
  k_main<<<256, 512, 139264, stream>>>(cidx, wemb, blin, outp, ws);
}